// Round 3
// baseline (173.989 us; speedup 1.0000x reference)
//
#include <hip/hip_runtime.h>
#include <hip/hip_bf16.h>

typedef __bf16 bf16;
typedef __bf16 bf16x8 __attribute__((ext_vector_type(8)));
typedef float f32x4 __attribute__((ext_vector_type(4)));
typedef uint4 u32x4;

// ---------------------------------------------------------------------------
// 256x256 8-phase GEMM, reg-staged (T14): C = A[M,K] @ B[N,K]^T, bf16, f32 acc.
// EPI=0: f32 store. EPI=1: sigmoid -> bf16 store.
// 512 thr = 8 waves (2M x 4N). BK=64. LDS 128KB (2 K-tile dbuf).
// Half h = 4T+q: q0=A.kk0, q1=B.kk0, q2=A.kk1, q3=B.kk1 (16KB each).
// Sub-phase sub of tile t (global phase p=4t+sub):
//   { ds_read frags ; global_load half p+6 -> regs ; barrier ; lgkm0 ;
//     16 MFMA ; ds_write half p+4 (vmcnt via precise reg-dep = counted ~4) ;
//     lgkm0 ; barrier }
// Swizzle on ds_write dest + ds_read addr (involution); global loads coalesced.
// ---------------------------------------------------------------------------
#define STG_LOAD(T_, Q_, S_)                                              \
  do {                                                                    \
    const bf16* base_ = ((Q_)&1) ? Brow : Arow;                           \
    const bf16* p_ = base_ + (((T_) << 6) + (((Q_) >> 1) << 5));          \
    stg##S_##a = *(const u32x4*)p_;                                       \
    stg##S_##b = *(const u32x4*)(p_ + rowstep);                           \
  } while (0)

#define STG_WRITE(T_, Q_, S_)                                             \
  do {                                                                    \
    char* d_ = smem + (((T_)&1) << 16) + (((Q_)&1) << 15) +               \
               (((Q_) >> 1) << 14) + wdst;                                \
    *(u32x4*)d_ = stg##S_##a;                                             \
    *(u32x4*)(d_ + 8192) = stg##S_##b;                                    \
  } while (0)

#define SUBPHASE(KK, QM, READB, LD_EN, LD_T, LD_Q, LD_S, WR_EN, WR_T, WR_Q, WR_S) \
  do {                                                                            \
    const int bufb_ = (t & 1) << 16;                                              \
    _Pragma("unroll") for (int i = 0; i < 4; ++i)                                 \
        afr[i] = *(const bf16x8*)(smem + bufb_ + ((KK) << 14) + abase0 +          \
                                  ((QM)*4 + i) * 1024);                           \
    if (READB) {                                                                  \
      _Pragma("unroll") for (int j = 0; j < 4; ++j)                               \
          bfr[j] = *(const bf16x8*)(smem + bufb_ + (1 << 15) + ((KK) << 14) +     \
                                    bbase0 + j * 1024);                           \
    }                                                                             \
    if (LD_EN) STG_LOAD(LD_T, LD_Q, LD_S);                                        \
    __builtin_amdgcn_sched_barrier(0);                                            \
    __builtin_amdgcn_s_barrier();                                                 \
    asm volatile("s_waitcnt lgkmcnt(0)" ::: "memory");                            \
    __builtin_amdgcn_sched_barrier(0);                                            \
    __builtin_amdgcn_s_setprio(1);                                                \
    _Pragma("unroll") for (int i = 0; i < 4; ++i)                                 \
      _Pragma("unroll") for (int j = 0; j < 4; ++j)                               \
        acc[(QM)*4 + i][j] = __builtin_amdgcn_mfma_f32_16x16x32_bf16(             \
            afr[i], bfr[j], acc[(QM)*4 + i][j], 0, 0, 0);                         \
    __builtin_amdgcn_s_setprio(0);                                                \
    __builtin_amdgcn_sched_barrier(0);                                            \
    if (WR_EN) STG_WRITE(WR_T, WR_Q, WR_S);                                       \
    asm volatile("s_waitcnt lgkmcnt(0)" ::: "memory");                            \
    __builtin_amdgcn_sched_barrier(0);                                            \
    __builtin_amdgcn_s_barrier();                                                 \
  } while (0)

template <int EPI>
__global__ __launch_bounds__(512, 2) void gemm8p(
    const bf16* __restrict__ A, const bf16* __restrict__ Bw,
    void* __restrict__ C, int M, int N, int K) {
  __shared__ __align__(16) char smem[131072];
  const int tid = threadIdx.x;
  const int lane = tid & 63;
  const int wave = tid >> 6;
  const int wr_ = wave >> 2;  // 0..1 (M)
  const int wc_ = wave & 3;   // 0..3 (N)

  const int nbN = N >> 8;
  const int nwg = gridDim.x;
  const int q8 = nwg >> 3;  // grids divisible by 8
  const int tile = ((int)blockIdx.x & 7) * q8 + ((int)blockIdx.x >> 3);
  const int m0 = (tile / nbN) << 8;
  const int n0 = (tile % nbN) << 8;

  // ---- staging constants: coalesced global loads, swizzled ds_write ----
  const int srow = tid >> 2;                     // 0..127 (row; +128 for 2nd)
  const int cchunk = (tid & 3) << 3;             // element col (8 elems/16B)
  const int swz = ((srow >> 1) & 3) << 4;        // same for srow+128
  const int wdst = srow * 64 + (((tid & 3) << 4) ^ swz);
  const size_t rowstep = (size_t)128 * K;
  const bf16* Arow = A + (size_t)(m0 + srow) * K + cchunk;
  const bf16* Brow = Bw + (size_t)(n0 + srow) * K + cchunk;
  u32x4 stg0a, stg0b, stg1a, stg1b, stg2a, stg2b, stg3a, stg3b;

  // ---- ds_read constants (identical image to r2: read at addr c^swz) ----
  const int lrow = lane & 15;
  const int rdofs = (((lane >> 4) & 3) << 4) ^ (((lrow >> 1) & 3) << 4);
  const int abase0 = wr_ * 8192 + lrow * 64 + rdofs;
  const int bbase0 = wc_ * 4096 + lrow * 64 + rdofs;

  f32x4 acc[8][4] = {};
  bf16x8 afr[4], bfr[4];

  const int nt = K >> 6;  // 16 for K=1024

  // ---- prologue: tile0 halves loaded+written; tile1 h4,h5 loads in flight --
  STG_LOAD(0, 0, 0); STG_LOAD(0, 1, 1); STG_LOAD(0, 2, 2); STG_LOAD(0, 3, 3);
  STG_WRITE(0, 0, 0); STG_WRITE(0, 1, 1); STG_WRITE(0, 2, 2); STG_WRITE(0, 3, 3);
  STG_LOAD(1, 0, 0); STG_LOAD(1, 1, 1);
  asm volatile("s_waitcnt lgkmcnt(0)" ::: "memory");
  __builtin_amdgcn_s_barrier();

  for (int t = 0; t < nt; ++t) {
    const bool ld01 = (t < nt - 1);
    const bool ld23 = (t < nt - 2);
    const bool wr = (t < nt - 1);
    SUBPHASE(0, 0, true,  ld01, t + 1, 2, 2,  wr, t + 1, 0, 0);
    SUBPHASE(0, 1, false, ld01, t + 1, 3, 3,  wr, t + 1, 1, 1);
    SUBPHASE(1, 0, true,  ld23, t + 2, 0, 0,  wr, t + 1, 2, 2);
    SUBPHASE(1, 1, false, ld23, t + 2, 1, 1,  wr, t + 1, 3, 3);
  }

  // ---- epilogue: C/D layout col=lane&15, row=(lane>>4)*4+reg ----
  const int col0 = n0 + (wc_ << 6) + lrow;
  const int rowb = m0 + (wr_ << 7) + ((lane >> 4) << 2);
#pragma unroll
  for (int i = 0; i < 8; ++i)
#pragma unroll
    for (int j = 0; j < 4; ++j)
#pragma unroll
      for (int r = 0; r < 4; ++r) {
        const size_t idx = (size_t)(rowb + i * 16 + r) * N + (col0 + j * 16);
        const float v = acc[i][j][r];
        if (EPI == 1) {
          ((bf16*)C)[idx] = (bf16)(1.0f / (1.0f + __expf(-v)));
        } else {
          ((float*)C)[idx] = v;
        }
      }
}

// ---------------------------------------------------------------------------
// Windowed Hamming attention + gate.  One thread per (b,s,h).
// ---------------------------------------------------------------------------
__global__ __launch_bounds__(256) void rosa_attn(
    const bf16* __restrict__ qkv, const float* __restrict__ emb0,
    const float* __restrict__ emb1, bf16* __restrict__ G) {
  const int t = blockIdx.x * 256 + threadIdx.x;
  const int row = t >> 7;
  const int h = t & 127;
  const int sp = row & 4095;

  const bf16* qptr = qkv + (size_t)row * 3072 + h * 8;
  bf16x8 qv = *(const bf16x8*)qptr;
  float qb[8], qsum = 0.f;
#pragma unroll
  for (int c = 0; c < 8; ++c) {
    qb[c] = (float)qv[c];
    qsum += qb[c];
  }

  float oacc[8] = {};
  float wsum = 0.f;
  const int wmax = (sp + 1 < 8) ? (sp + 1) : 8;
  const float scale = 0.35355339059327373f;

  for (int d = 0; d < wmax; ++d) {
    const bf16* base = qkv + (size_t)(row - d) * 3072 + h * 8;
    bf16x8 kv = *(const bf16x8*)(base + 1024);
    bf16x8 vv = *(const bf16x8*)(base + 2048);
    float dot = 0.f, ksum = 0.f;
#pragma unroll
    for (int c = 0; c < 8; ++c) {
      const float kb = (float)kv[c];
      dot += qb[c] * kb;
      ksum += kb;
    }
    const float score = (8.0f + 2.0f * dot - qsum - ksum) * scale;
    const float w = __expf(score);
    wsum += w;
#pragma unroll
    for (int c = 0; c < 8; ++c) oacc[c] += w * (float)vv[c];
  }

  const float inv = 1.0f / wsum;
  const int e0i = h * 8;
  bf16x8 outv;
#pragma unroll
  for (int c = 0; c < 8; ++c) {
    const float o = oacc[c] * inv;
    const float e0 = emb0[e0i + c], e1 = emb1[e0i + c];
    outv[c] = (bf16)(e0 + (e1 - e0) * o);
  }
  *(bf16x8*)(G + (size_t)row * 1024 + h * 8) = outv;
}

// ---------------------------------------------------------------------------
__global__ __launch_bounds__(256) void cvt_f32_bf16(
    const float* __restrict__ src, bf16* __restrict__ dst, int n) {
  const int i = (blockIdx.x * 256 + threadIdx.x) * 8;
  if (i >= n) return;
  const float4 a = *(const float4*)(src + i);
  const float4 b = *(const float4*)(src + i + 4);
  bf16x8 o;
  o[0] = (bf16)a.x; o[1] = (bf16)a.y; o[2] = (bf16)a.z; o[3] = (bf16)a.w;
  o[4] = (bf16)b.x; o[5] = (bf16)b.y; o[6] = (bf16)b.z; o[7] = (bf16)b.w;
  *(bf16x8*)(dst + i) = o;
}

// ---------------------------------------------------------------------------
extern "C" void kernel_launch(void* const* d_in, const int* in_sizes, int n_in,
                              void* d_out, int out_size, void* d_ws,
                              size_t ws_size, hipStream_t stream) {
  const float* X = (const float*)d_in[0];
  const float* Wq = (const float*)d_in[1];
  const float* Wk = (const float*)d_in[2];
  const float* Wv = (const float*)d_in[3];
  const float* Wo = (const float*)d_in[4];
  const float* emb0 = (const float*)d_in[5];
  const float* emb1 = (const float*)d_in[6];

  char* ws = (char*)d_ws;
  bf16* Xb    = (bf16*)(ws + 0);          // 8192*1024   (16 MB)
  bf16* Wqkvb = (bf16*)(ws + 16777216);   // 3072*1024   (6 MB)
  bf16* Wob   = (bf16*)(ws + 23068672);   // 1024*1024   (2 MB)
  bf16* QKVb  = (bf16*)(ws + 25165824);   // 8192*3072   (48 MB)
  bf16* G     = (bf16*)(ws + 75497472);   // 8192*1024   (16 MB)
  float* out  = (float*)d_out;

  cvt_f32_bf16<<<4096, 256, 0, stream>>>(X, Xb, 8388608);
  cvt_f32_bf16<<<512, 256, 0, stream>>>(Wq, Wqkvb, 1048576);
  cvt_f32_bf16<<<512, 256, 0, stream>>>(Wk, Wqkvb + 1048576, 1048576);
  cvt_f32_bf16<<<512, 256, 0, stream>>>(Wv, Wqkvb + 2097152, 1048576);
  cvt_f32_bf16<<<512, 256, 0, stream>>>(Wo, Wob, 1048576);

  // fused QKV projection + sigmoid -> bf16 (M=8192, N=3072, K=1024)
  gemm8p<1><<<384, 512, 0, stream>>>(Xb, Wqkvb, QKVb, 8192, 3072, 1024);

  // windowed attention + gate -> bf16
  rosa_attn<<<4096, 256, 0, stream>>>(QKVb, emb0, emb1, G);

  // output projection -> f32 (M=8192, N=1024, K=1024)
  gemm8p<0><<<128, 512, 0, stream>>>(G, Wob, out, 8192, 1024, 1024);
}

// Round 4
// 139.072 us; speedup vs baseline: 1.2511x; 1.2511x over previous
//
#include <hip/hip_runtime.h>
#include <hip/hip_bf16.h>

typedef __bf16 bf16;
typedef __bf16 bf16x8 __attribute__((ext_vector_type(8)));
typedef float f32x4 __attribute__((ext_vector_type(4)));

__device__ __forceinline__ void gload_lds16(const void* g, void* l) {
  __builtin_amdgcn_global_load_lds(
      (const __attribute__((address_space(1))) void*)g,
      (__attribute__((address_space(3))) void*)l, 16, 0, 0);
}

// ---------------------------------------------------------------------------
// C = A[M,K] @ B[N,K]^T (row-major, K inner). bf16 in, f32 accum.
// EPI=0: f32 store. EPI=1: sigmoid -> bf16 store.
// 128x128 tile, BK=32, 256 thr = 4 waves (2x2), 4x4 MFMA 16x16x32 per wave.
// T3 2-phase: LDS double buffer (2 x 16KB), ONE barrier per K-iter:
//   { STAGE(t+1 -> buf^1) ; ds_read frags(buf) ; 16 MFMA ; __syncthreads() }
// Staging drain (vmcnt0 inside syncthreads) overlaps ds_read+MFMA + other
// blocks (4 blocks/CU target).  T2 swizzle (r2-validated, 0 conflicts):
// linear gload_lds dest + source col ^= ((row>>1)&3)<<4 + same XOR on ds_read.
// ---------------------------------------------------------------------------
template <int EPI>
__global__ __launch_bounds__(256, 4) void gemm_bt(
    const bf16* __restrict__ A, const bf16* __restrict__ Bw,
    void* __restrict__ C, int M, int N, int K) {
  __shared__ __align__(16) char smem[32768];  // buf b: A @ b*16K, B @ b*16K+8K
  const int tid = threadIdx.x;
  const int lane = tid & 63;
  const int wave = tid >> 6;

  const int nb = N >> 7;
  const int nwg = gridDim.x;
  const int q8 = nwg >> 3;  // grids divisible by 8
  const int tile = ((int)blockIdx.x & 7) * q8 + ((int)blockIdx.x >> 3);
  const int m0 = (tile / nb) << 7;
  const int n0 = (tile % nb) << 7;

  const int wm = (wave >> 1) << 6;
  const int wn = (wave & 1) << 6;

  f32x4 acc[4][4] = {};

  // staging constants: thread covers 4 chunks (chunk = wave + 4c), 16 rows each
  const int r_in = lane >> 2;                        // row within 16-row chunk
  const int swz = ((lane >> 3) & 3) << 4;            // ((r_in>>1)&3)<<4
  const int scol = (((lane & 3) << 4) ^ swz) >> 1;   // source col (elements)
  const int ldst_lin = lane << 4;                    // linear dest within chunk

  auto stage = [&](int t, int buf) {
    const int k0 = t << 5;
#pragma unroll
    for (int c = 0; c < 4; ++c) {
      const int chunk = wave + (c << 2);  // wave-uniform 0..15
      char* ldst = smem + (buf << 14) + chunk * 1024 + ldst_lin;
      const bf16* gsrc;
      if (chunk < 8) {
        const int row = m0 + (chunk << 4) + r_in;
        gsrc = A + (size_t)row * K + k0 + scol;
      } else {
        const int row = n0 + ((chunk - 8) << 4) + r_in;
        gsrc = Bw + (size_t)row * K + k0 + scol;
      }
      gload_lds16(gsrc, ldst);
    }
  };

  // ds_read constants
  const int lrow = lane & 15;
  const int koff = ((lane >> 4) << 4) ^ (((lrow >> 1) & 3) << 4);

  const int nt = K >> 5;  // 32 for K=1024

  stage(0, 0);
  __syncthreads();

  for (int t = 0; t < nt; ++t) {
    const int buf = t & 1;
    if (t + 1 < nt) stage(t + 1, buf ^ 1);

    bf16x8 af[4], bg[4];
    const char* base = smem + (buf << 14);
#pragma unroll
    for (int i = 0; i < 4; ++i) {
      af[i] = *(const bf16x8*)(base + (wm + (i << 4) + lrow) * 64 + koff);
      bg[i] = *(const bf16x8*)(base + 8192 + (wn + (i << 4) + lrow) * 64 + koff);
    }
#pragma unroll
    for (int i = 0; i < 4; ++i)
#pragma unroll
      for (int j = 0; j < 4; ++j)
        acc[i][j] =
            __builtin_amdgcn_mfma_f32_16x16x32_bf16(af[i], bg[j], acc[i][j], 0, 0, 0);

    __syncthreads();  // drains this iter's stage (overlapped) + syncs LDS reuse
  }

  // epilogue: C/D layout col=lane&15, row=(lane>>4)*4+reg
  const int col0 = n0 + wn + (lane & 15);
  const int rowb = m0 + wm + ((lane >> 4) << 2);
#pragma unroll
  for (int i = 0; i < 4; ++i)
#pragma unroll
    for (int j = 0; j < 4; ++j)
#pragma unroll
      for (int r = 0; r < 4; ++r) {
        const size_t idx = (size_t)(rowb + (i << 4) + r) * N + (col0 + (j << 4));
        const float v = acc[i][j][r];
        if (EPI == 1) {
          ((bf16*)C)[idx] = (bf16)(1.0f / (1.0f + __expf(-v)));
        } else {
          ((float*)C)[idx] = v;
        }
      }
}

// ---------------------------------------------------------------------------
// Windowed Hamming attention + gate.  One thread per (b,s,h).
// ---------------------------------------------------------------------------
__global__ __launch_bounds__(256) void rosa_attn(
    const bf16* __restrict__ qkv, const float* __restrict__ emb0,
    const float* __restrict__ emb1, bf16* __restrict__ G) {
  const int t = blockIdx.x * 256 + threadIdx.x;
  const int row = t >> 7;
  const int h = t & 127;
  const int sp = row & 4095;

  const bf16* qptr = qkv + (size_t)row * 3072 + h * 8;
  bf16x8 qv = *(const bf16x8*)qptr;
  float qb[8], qsum = 0.f;
#pragma unroll
  for (int c = 0; c < 8; ++c) {
    qb[c] = (float)qv[c];
    qsum += qb[c];
  }

  float oacc[8] = {};
  float wsum = 0.f;
  const int wmax = (sp + 1 < 8) ? (sp + 1) : 8;
  const float scale = 0.35355339059327373f;

  for (int d = 0; d < wmax; ++d) {
    const bf16* base = qkv + (size_t)(row - d) * 3072 + h * 8;
    bf16x8 kv = *(const bf16x8*)(base + 1024);
    bf16x8 vv = *(const bf16x8*)(base + 2048);
    float dot = 0.f, ksum = 0.f;
#pragma unroll
    for (int c = 0; c < 8; ++c) {
      const float kb = (float)kv[c];
      dot += qb[c] * kb;
      ksum += kb;
    }
    const float score = (8.0f + 2.0f * dot - qsum - ksum) * scale;
    const float w = __expf(score);
    wsum += w;
#pragma unroll
    for (int c = 0; c < 8; ++c) oacc[c] += w * (float)vv[c];
  }

  const float inv = 1.0f / wsum;
  const int e0i = h * 8;
  bf16x8 outv;
#pragma unroll
  for (int c = 0; c < 8; ++c) {
    const float o = oacc[c] * inv;
    const float e0 = emb0[e0i + c], e1 = emb1[e0i + c];
    outv[c] = (bf16)(e0 + (e1 - e0) * o);
  }
  *(bf16x8*)(G + (size_t)row * 1024 + h * 8) = outv;
}

// ---------------------------------------------------------------------------
__global__ __launch_bounds__(256) void cvt_f32_bf16(
    const float* __restrict__ src, bf16* __restrict__ dst, int n) {
  const int i = (blockIdx.x * 256 + threadIdx.x) * 8;
  if (i >= n) return;
  const float4 a = *(const float4*)(src + i);
  const float4 b = *(const float4*)(src + i + 4);
  bf16x8 o;
  o[0] = (bf16)a.x; o[1] = (bf16)a.y; o[2] = (bf16)a.z; o[3] = (bf16)a.w;
  o[4] = (bf16)b.x; o[5] = (bf16)b.y; o[6] = (bf16)b.z; o[7] = (bf16)b.w;
  *(bf16x8*)(dst + i) = o;
}

// ---------------------------------------------------------------------------
extern "C" void kernel_launch(void* const* d_in, const int* in_sizes, int n_in,
                              void* d_out, int out_size, void* d_ws,
                              size_t ws_size, hipStream_t stream) {
  const float* X = (const float*)d_in[0];
  const float* Wq = (const float*)d_in[1];
  const float* Wk = (const float*)d_in[2];
  const float* Wv = (const float*)d_in[3];
  const float* Wo = (const float*)d_in[4];
  const float* emb0 = (const float*)d_in[5];
  const float* emb1 = (const float*)d_in[6];

  char* ws = (char*)d_ws;
  bf16* Xb    = (bf16*)(ws + 0);          // 8192*1024   (16 MB)
  bf16* Wqkvb = (bf16*)(ws + 16777216);   // 3072*1024   (6 MB)
  bf16* Wob   = (bf16*)(ws + 23068672);   // 1024*1024   (2 MB)
  bf16* QKVb  = (bf16*)(ws + 25165824);   // 8192*3072   (48 MB)
  bf16* G     = (bf16*)(ws + 75497472);   // 8192*1024   (16 MB)
  float* out  = (float*)d_out;

  cvt_f32_bf16<<<4096, 256, 0, stream>>>(X, Xb, 8388608);
  cvt_f32_bf16<<<512, 256, 0, stream>>>(Wq, Wqkvb, 1048576);
  cvt_f32_bf16<<<512, 256, 0, stream>>>(Wk, Wqkvb + 1048576, 1048576);
  cvt_f32_bf16<<<512, 256, 0, stream>>>(Wv, Wqkvb + 2097152, 1048576);
  cvt_f32_bf16<<<512, 256, 0, stream>>>(Wo, Wob, 1048576);

  // fused QKV projection + sigmoid -> bf16 (M=8192, N=3072, K=1024)
  gemm_bt<1><<<64 * 24, 256, 0, stream>>>(Xb, Wqkvb, QKVb, 8192, 3072, 1024);

  // windowed attention + gate -> bf16
  rosa_attn<<<4096, 256, 0, stream>>>(QKVb, emb0, emb1, G);

  // output projection -> f32 (M=8192, N=1024, K=1024)
  gemm_bt<0><<<64 * 8, 256, 0, stream>>>(G, Wob, out, 8192, 1024, 1024);
}

// Round 5
// 137.844 us; speedup vs baseline: 1.2622x; 1.0089x over previous
//
#include <hip/hip_runtime.h>
#include <hip/hip_bf16.h>

typedef __bf16 bf16;
typedef __bf16 bf16x8 __attribute__((ext_vector_type(8)));
typedef float f32x4 __attribute__((ext_vector_type(4)));

__device__ __forceinline__ void gload_lds16(const void* g, void* l) {
  __builtin_amdgcn_global_load_lds(
      (const __attribute__((address_space(1))) void*)g,
      (__attribute__((address_space(3))) void*)l, 16, 0, 0);
}

// ---------------------------------------------------------------------------
// C = A[M,K] @ B[N,K]^T (row-major, K inner). bf16 in, f32 accum.
// EPI=0: f32 store. EPI=1: sigmoid -> bf16 store.
// 128x128 tile, BK=32, 256 thr = 4 waves (2x2), 4x4 MFMA 16x16x32 per wave.
// T3+T4: TRIPLE-buffered LDS (3 x 16KB), one raw s_barrier/iter, counted
// vmcnt(4) (stage(t) landed, stage(t+1) in flight, stage(t+2) issued after
// the barrier).  Loads get ~2 iterations to land -> no per-iter L2 stall.
// Hazard proof: stage(t+2) writes buf((t-1)%3); every wave's ds_reads of
// that buf completed (lgkmcnt(0) before MFMA) before barrier(t); every
// wave's vmcnt(4) before barrier(t) => tile t fully in LDS for all waves.
// T2 swizzle (r2/r4-validated, 0 conflicts): linear gload_lds dest +
// source col ^= ((row>>1)&3)<<4 + same XOR on ds_read addr.
// ---------------------------------------------------------------------------
template <int EPI>
__global__ __launch_bounds__(256, 3) void gemm_bt(
    const bf16* __restrict__ A, const bf16* __restrict__ Bw,
    void* __restrict__ C, int M, int N, int K) {
  __shared__ __align__(16) char smem[49152];  // buf b at b*16K: A 8K, B 8K
  const int tid = threadIdx.x;
  const int lane = tid & 63;
  const int wave = tid >> 6;

  const int nb = N >> 7;
  const int nwg = gridDim.x;
  const int q8 = nwg >> 3;  // grids divisible by 8
  const int tile = ((int)blockIdx.x & 7) * q8 + ((int)blockIdx.x >> 3);
  const int m0 = (tile / nb) << 7;
  const int n0 = (tile % nb) << 7;

  const int wm = (wave >> 1) << 6;
  const int wn = (wave & 1) << 6;

  f32x4 acc[4][4] = {};

  // staging constants: thread covers 4 chunks (chunk = wave + 4c), 16 rows each
  const int r_in = lane >> 2;                        // row within 16-row chunk
  const int swz = ((lane >> 3) & 3) << 4;            // ((r_in>>1)&3)<<4
  const int scol = (((lane & 3) << 4) ^ swz) >> 1;   // source col (elements)
  const int ldst_lin = lane << 4;                    // linear dest within chunk

  auto stage = [&](int t, int buf) {
    const int k0 = t << 5;
#pragma unroll
    for (int c = 0; c < 4; ++c) {
      const int chunk = wave + (c << 2);  // wave-uniform 0..15
      char* ldst = smem + buf * 16384 + chunk * 1024 + ldst_lin;
      const bf16* gsrc;
      if (chunk < 8) {
        const int row = m0 + (chunk << 4) + r_in;
        gsrc = A + (size_t)row * K + k0 + scol;
      } else {
        const int row = n0 + ((chunk - 8) << 4) + r_in;
        gsrc = Bw + (size_t)row * K + k0 + scol;
      }
      gload_lds16(gsrc, ldst);
    }
  };

  // ds_read constants
  const int lrow = lane & 15;
  const int koff = ((lane >> 4) << 4) ^ (((lrow >> 1) & 3) << 4);

  const int nt = K >> 5;  // 32 for K=1024

  stage(0, 0);
  stage(1, 1);

  for (int t = 0; t < nt; ++t) {
    const int buf = t % 3;
    if (t == nt - 1) {
      asm volatile("s_waitcnt vmcnt(0)" ::: "memory");
    } else {
      asm volatile("s_waitcnt vmcnt(4)" ::: "memory");  // stage(t) landed
    }
    __builtin_amdgcn_s_barrier();
    __builtin_amdgcn_sched_barrier(0);

    bf16x8 af[4], bg[4];
    const char* base = smem + buf * 16384;
#pragma unroll
    for (int i = 0; i < 4; ++i) {
      af[i] = *(const bf16x8*)(base + (wm + (i << 4) + lrow) * 64 + koff);
      bg[i] = *(const bf16x8*)(base + 8192 + (wn + (i << 4) + lrow) * 64 + koff);
    }

    if (t + 2 < nt) stage(t + 2, (t + 2) % 3);

    asm volatile("s_waitcnt lgkmcnt(0)" ::: "memory");  // ds_reads complete
    __builtin_amdgcn_sched_barrier(0);                  // rule #18

#pragma unroll
    for (int i = 0; i < 4; ++i)
#pragma unroll
      for (int j = 0; j < 4; ++j)
        acc[i][j] =
            __builtin_amdgcn_mfma_f32_16x16x32_bf16(af[i], bg[j], acc[i][j], 0, 0, 0);
  }

  // epilogue: C/D layout col=lane&15, row=(lane>>4)*4+reg
  const int col0 = n0 + wn + (lane & 15);
  const int rowb = m0 + wm + ((lane >> 4) << 2);
#pragma unroll
  for (int i = 0; i < 4; ++i)
#pragma unroll
    for (int j = 0; j < 4; ++j)
#pragma unroll
      for (int r = 0; r < 4; ++r) {
        const size_t idx = (size_t)(rowb + (i << 4) + r) * N + (col0 + (j << 4));
        const float v = acc[i][j][r];
        if (EPI == 1) {
          ((bf16*)C)[idx] = (bf16)(1.0f / (1.0f + __expf(-v)));
        } else {
          ((float*)C)[idx] = v;
        }
      }
}

// ---------------------------------------------------------------------------
// Windowed Hamming attention + gate.  One thread per (b,s,h).
// ---------------------------------------------------------------------------
__global__ __launch_bounds__(256) void rosa_attn(
    const bf16* __restrict__ qkv, const float* __restrict__ emb0,
    const float* __restrict__ emb1, bf16* __restrict__ G) {
  const int t = blockIdx.x * 256 + threadIdx.x;
  const int row = t >> 7;
  const int h = t & 127;
  const int sp = row & 4095;

  const bf16* qptr = qkv + (size_t)row * 3072 + h * 8;
  bf16x8 qv = *(const bf16x8*)qptr;
  float qb[8], qsum = 0.f;
#pragma unroll
  for (int c = 0; c < 8; ++c) {
    qb[c] = (float)qv[c];
    qsum += qb[c];
  }

  float oacc[8] = {};
  float wsum = 0.f;
  const int wmax = (sp + 1 < 8) ? (sp + 1) : 8;
  const float scale = 0.35355339059327373f;

  for (int d = 0; d < wmax; ++d) {
    const bf16* base = qkv + (size_t)(row - d) * 3072 + h * 8;
    bf16x8 kv = *(const bf16x8*)(base + 1024);
    bf16x8 vv = *(const bf16x8*)(base + 2048);
    float dot = 0.f, ksum = 0.f;
#pragma unroll
    for (int c = 0; c < 8; ++c) {
      const float kb = (float)kv[c];
      dot += qb[c] * kb;
      ksum += kb;
    }
    const float score = (8.0f + 2.0f * dot - qsum - ksum) * scale;
    const float w = __expf(score);
    wsum += w;
#pragma unroll
    for (int c = 0; c < 8; ++c) oacc[c] += w * (float)vv[c];
  }

  const float inv = 1.0f / wsum;
  const int e0i = h * 8;
  bf16x8 outv;
#pragma unroll
  for (int c = 0; c < 8; ++c) {
    const float o = oacc[c] * inv;
    const float e0 = emb0[e0i + c], e1 = emb1[e0i + c];
    outv[c] = (bf16)(e0 + (e1 - e0) * o);
  }
  *(bf16x8*)(G + (size_t)row * 1024 + h * 8) = outv;
}

// ---------------------------------------------------------------------------
__global__ __launch_bounds__(256) void cvt_f32_bf16(
    const float* __restrict__ src, bf16* __restrict__ dst, int n) {
  const int i = (blockIdx.x * 256 + threadIdx.x) * 8;
  if (i >= n) return;
  const float4 a = *(const float4*)(src + i);
  const float4 b = *(const float4*)(src + i + 4);
  bf16x8 o;
  o[0] = (bf16)a.x; o[1] = (bf16)a.y; o[2] = (bf16)a.z; o[3] = (bf16)a.w;
  o[4] = (bf16)b.x; o[5] = (bf16)b.y; o[6] = (bf16)b.z; o[7] = (bf16)b.w;
  *(bf16x8*)(dst + i) = o;
}

// ---------------------------------------------------------------------------
extern "C" void kernel_launch(void* const* d_in, const int* in_sizes, int n_in,
                              void* d_out, int out_size, void* d_ws,
                              size_t ws_size, hipStream_t stream) {
  const float* X = (const float*)d_in[0];
  const float* Wq = (const float*)d_in[1];
  const float* Wk = (const float*)d_in[2];
  const float* Wv = (const float*)d_in[3];
  const float* Wo = (const float*)d_in[4];
  const float* emb0 = (const float*)d_in[5];
  const float* emb1 = (const float*)d_in[6];

  char* ws = (char*)d_ws;
  bf16* Xb    = (bf16*)(ws + 0);          // 8192*1024   (16 MB)
  bf16* Wqkvb = (bf16*)(ws + 16777216);   // 3072*1024   (6 MB)
  bf16* Wob   = (bf16*)(ws + 23068672);   // 1024*1024   (2 MB)
  bf16* QKVb  = (bf16*)(ws + 25165824);   // 8192*3072   (48 MB)
  bf16* G     = (bf16*)(ws + 75497472);   // 8192*1024   (16 MB)
  float* out  = (float*)d_out;

  cvt_f32_bf16<<<4096, 256, 0, stream>>>(X, Xb, 8388608);
  cvt_f32_bf16<<<512, 256, 0, stream>>>(Wq, Wqkvb, 1048576);
  cvt_f32_bf16<<<512, 256, 0, stream>>>(Wk, Wqkvb + 1048576, 1048576);
  cvt_f32_bf16<<<512, 256, 0, stream>>>(Wv, Wqkvb + 2097152, 1048576);
  cvt_f32_bf16<<<512, 256, 0, stream>>>(Wo, Wob, 1048576);

  // fused QKV projection + sigmoid -> bf16 (M=8192, N=3072, K=1024)
  gemm_bt<1><<<64 * 24, 256, 0, stream>>>(Xb, Wqkvb, QKVb, 8192, 3072, 1024);

  // windowed attention + gate -> bf16
  rosa_attn<<<4096, 256, 0, stream>>>(QKVb, emb0, emb1, G);

  // output projection -> f32 (M=8192, N=1024, K=1024)
  gemm_bt<0><<<64 * 8, 256, 0, stream>>>(G, Wob, out, 8192, 1024, 1024);
}